// Round 10
// baseline (316.684 us; speedup 1.0000x reference)
//
#include <hip/hip_runtime.h>
#include <hip/hip_cooperative_groups.h>
#include <hip/hip_bf16.h>

namespace cg = cooperative_groups;

// GCN 2-layer (R10): 4-dispatch pipeline.
//   [coop front: bin -> grid.sync -> csr -> grid.sync -> gemm1] ->
//   agg1 -> gemm2 -> agg2
// R9 lesson: NEVER fuse a compute phase into a grid-limited (196-block)
// kernel — gemm1 starved at 1 block/CU (occupancy 8%, 84us). The coop
// front-end keeps every phase at its natural grid (bin 391 / csr 196 /
// gemm1 512 grid-stride) with grid.sync between, no launch-bounds cap
// (R5 lesson: forcing the envelope -> VGPR 64 + spills). Latency-critical
// agg kernels stay OUTSIDE (R5 lesson). Cursor-free binning (R9-proven,
// no memset); csr reads cells COMPACTLY via cnt[b][c] (fixes R9's 3x
// guarded-slot amplification). CSR rows phase-sorted by src>>13
// (FETCH 159->88 MB, R4-proven). agg: 4 nodes/wave, 16-lane quarters,
// 8 gathers in flight (R8-proven). NO LDS float atomics (R2/R3 lesson).
// GEMM: MFMA bf16 hi/lo split (fp32-equivalent accuracy).

#define NDIM 64
#define BSHIFT 9                 // 512 nodes per bucket
#define BNODES (1 << BSHIFT)
#define BCAP 10240               // csr edge capacity per bucket (avg 8163)
#define CHUNK 4096               // edges per binning block
#define CAPC 64                  // slots per (bucket,chunk) cell (avg ~21)
#define CSHIFT 6
#define MAXCHUNK 512             // ccnt LDS bound (nchunk = 391)
#define PHASES 13                // src phase = src >> PSHIFT; 13*8192 >= N
#define PSHIFT 13

typedef float v2f __attribute__((ext_vector_type(2)));
typedef __attribute__((ext_vector_type(8))) short short8b;  // 8 bf16
typedef __attribute__((ext_vector_type(4))) float f32x4;

__device__ __forceinline__ unsigned f2bf_rne(float f) {
  unsigned u = __float_as_uint(f);
  return (u + 0x7fffu + ((u >> 16) & 1u)) >> 16;  // RNE (finite values only)
}

struct BinSh {
  int lcnt[256], lbase[256], lcur[256], tscan[256];
  int2 stage[CHUNK];             // 32 KB; total 36 KB
};
struct CsrSh {
  int deg[BNODES], rpl[BNODES], tscan[256], ccnt[MAXCHUNK];
  int pcnt[BNODES * PHASES];     // 26.6 KB; total ~33.6 KB
};
union FrontSh {
  BinSh b;                       // 36 KB (union size) -> 4 blocks/CU max
  CsrSh c;
  ushort g[4][16 * NDIM];        // 8 KB per-wave gemm stage
};

// ---- cooperative front-end: bin -> csr -> gemm1 ----
__global__ __launch_bounds__(256) void front_kernel(
    const int* __restrict__ src, const int* __restrict__ dst,
    unsigned* __restrict__ binned, int* __restrict__ cnt,
    int* __restrict__ rowbeg, int* __restrict__ rowend,
    int* __restrict__ csr_src, float* __restrict__ dinv,
    const float* __restrict__ X, const float* __restrict__ W,
    ushort* __restrict__ hsb, int n, int nedges, int nbuck, int nchunk) {
  __shared__ __align__(16) FrontSh sh;
  cg::grid_group grid = cg::this_grid();
  const int t = threadIdx.x;

  // ---- phase 1: cursor-free binning (grid-stride over chunks; R9-proven) ----
  for (int c = blockIdx.x; c < nchunk; c += gridDim.x) {
    const int i0 = c * CHUNK;
    int iend = i0 + CHUNK; if (iend > nedges) iend = nedges;
    sh.b.lcnt[t] = 0;
    __syncthreads();
    for (int i = i0 + t; i < iend; i += 256)
      atomicAdd(&sh.b.lcnt[dst[i] >> BSHIFT], 1);
    __syncthreads();
    sh.b.tscan[t] = sh.b.lcnt[t];
    __syncthreads();
    for (int off = 1; off < 256; off <<= 1) {
      int tv = (t >= off) ? sh.b.tscan[t - off] : 0;
      __syncthreads();
      sh.b.tscan[t] += tv;
      __syncthreads();
    }
    sh.b.lbase[t] = sh.b.tscan[t] - sh.b.lcnt[t];
    sh.b.lcur[t] = sh.b.lbase[t];
    __syncthreads();
    for (int i = i0 + t; i < iend; i += 256) {
      int s = src[i], d = dst[i];
      int p = atomicAdd(&sh.b.lcur[d >> BSHIFT], 1);
      sh.b.stage[p] = make_int2(s, d);
    }
    __syncthreads();
    const int m = iend - i0;
    for (int i = t; i < m; i += 256) {
      int2 pr = sh.b.stage[i];
      int b = pr.y >> BSHIFT;
      int off = i - sh.b.lbase[b];
      if (off < CAPC)   // Poisson(21): P(>64) ~ 1e-13 — never drops
        binned[(((size_t)b * nchunk + c) << CSHIFT) + off] =
            (((unsigned)(pr.y & (BNODES - 1))) << 17) | (unsigned)pr.x;
    }
    if (t < nbuck) cnt[t * nchunk + c] = (sh.b.lcnt[t] < CAPC) ? sh.b.lcnt[t] : CAPC;
    __syncthreads();  // before next iteration reuses sh.b
  }
  grid.sync();

  // ---- phase 2: per-bucket CSR build, rows phase-sorted; COMPACT cell reads ----
  for (int b = blockIdx.x; b < nbuck; b += gridDim.x) {
    const int node0 = b << BSHIFT;
    int ncnt = n - node0; if (ncnt > BNODES) ncnt = BNODES;
    const int e0 = b * BCAP;
    const size_t bbase = ((size_t)b * nchunk) << CSHIFT;
    for (int i = t; i < BNODES * PHASES; i += 256) sh.c.pcnt[i] = 0;
    for (int i = t; i < nchunk; i += 256) sh.c.ccnt[i] = cnt[b * nchunk + i];
    __syncthreads();
    for (int c = t; c < nchunk; c += 256) {   // histogram, compact per cell
      const int ne = sh.c.ccnt[c];
      const unsigned* p = binned + bbase + ((size_t)c << CSHIFT);
      for (int i = 0; i < ne; ++i) {
        unsigned u = p[i];
        atomicAdd(&sh.c.pcnt[(u >> 17) * PHASES + ((u & 0x1FFFFu) >> PSHIFT)], 1);
      }
    }
    __syncthreads();
    for (int i = t; i < BNODES; i += 256) {   // per-node exclusive phase scan
      int s = 0;
#pragma unroll
      for (int p = 0; p < PHASES; ++p) {
        int cv = sh.c.pcnt[i * PHASES + p];
        sh.c.pcnt[i * PHASES + p] = s;
        s += cv;
      }
      sh.c.deg[i] = s;
    }
    __syncthreads();
    int d0 = sh.c.deg[2 * t], d1 = sh.c.deg[2 * t + 1];
    int ps = d0 + d1;
    sh.c.tscan[t] = ps;
    __syncthreads();
    for (int off = 1; off < 256; off <<= 1) {
      int tv = (t >= off) ? sh.c.tscan[t - off] : 0;
      __syncthreads();
      sh.c.tscan[t] += tv;
      __syncthreads();
    }
    int eb = sh.c.tscan[t] - ps;
    sh.c.rpl[2 * t] = eb;
    sh.c.rpl[2 * t + 1] = eb + d0;
    __syncthreads();
    for (int i = t; i < ncnt; i += 256) {
      rowbeg[node0 + i] = e0 + sh.c.rpl[i];
      rowend[node0 + i] = e0 + sh.c.rpl[i] + sh.c.deg[i];
      dinv[node0 + i] = rsqrtf((float)sh.c.deg[i] + 1.0f);
    }
    __syncthreads();
    for (int c = t; c < nchunk; c += 256) {   // phase-sorted scatter
      const int ne = sh.c.ccnt[c];
      const unsigned* p = binned + bbase + ((size_t)c << CSHIFT);
      for (int i = 0; i < ne; ++i) {
        unsigned u = p[i];
        int nd = u >> 17;
        int s = (int)(u & 0x1FFFFu);
        int pos = sh.c.rpl[nd] + atomicAdd(&sh.c.pcnt[nd * PHASES + (s >> PSHIFT)], 1);
        csr_src[e0 + pos] = s;
      }
    }
    __syncthreads();  // before next iteration reuses sh.c
  }
  grid.sync();

  // ---- phase 3: gemm1 (hi/lo MFMA, fp32 X), per-wave tiles, barrier-free ----
  const int l = t & 63;
  const int wvq = t >> 6;
  const int lrow = l & 15;
  const int kg = l >> 4;
  short8b Whi[4][2], Wlo[4][2];
#pragma unroll
  for (int ct = 0; ct < 4; ++ct) {
#pragma unroll
    for (int ks = 0; ks < 2; ++ks) {
      const int c = ct * 16 + lrow;
      const int k0 = ks * 32 + kg * 8;
#pragma unroll
      for (int i = 0; i < 8; ++i) {
        float w = W[(k0 + i) * NDIM + c];
        unsigned hb = f2bf_rne(w);
        float hf = __uint_as_float(hb << 16);
        Whi[ct][ks][i] = (short)hb;
        Wlo[ct][ks][i] = (short)f2bf_rne(w - hf);
      }
    }
  }
  const int tiles = (n + 15) >> 4;
  for (int ti = blockIdx.x * 4 + wvq; ti < tiles; ti += gridDim.x * 4) {
    const int row0 = ti << 4;
    const int r = row0 + lrow;
    short8b Ahi[2], Alo[2];
    const float4* Xf = (const float4*)X;
#pragma unroll
    for (int ks = 0; ks < 2; ++ks) {
      float4 xa = make_float4(0.f, 0.f, 0.f, 0.f);
      float4 xb = make_float4(0.f, 0.f, 0.f, 0.f);
      if (r < n) {
        xa = Xf[(size_t)r * 16 + ks * 8 + kg * 2];
        xb = Xf[(size_t)r * 16 + ks * 8 + kg * 2 + 1];
      }
      float xs[8] = {xa.x, xa.y, xa.z, xa.w, xb.x, xb.y, xb.z, xb.w};
#pragma unroll
      for (int i = 0; i < 8; ++i) {
        unsigned hb = f2bf_rne(xs[i]);
        float hf = __uint_as_float(hb << 16);
        Ahi[ks][i] = (short)hb;
        Alo[ks][i] = (short)f2bf_rne(xs[i] - hf);
      }
    }
    f32x4 acc[4];
#pragma unroll
    for (int ct = 0; ct < 4; ++ct) {
      f32x4 a = {0.f, 0.f, 0.f, 0.f};
#pragma unroll
      for (int ks = 0; ks < 2; ++ks) {
        a = __builtin_amdgcn_mfma_f32_16x16x32_bf16(Ahi[ks], Whi[ct][ks], a, 0, 0, 0);
        a = __builtin_amdgcn_mfma_f32_16x16x32_bf16(Ahi[ks], Wlo[ct][ks], a, 0, 0, 0);
        a = __builtin_amdgcn_mfma_f32_16x16x32_bf16(Alo[ks], Whi[ct][ks], a, 0, 0, 0);
      }
      acc[ct] = a;
    }
#pragma unroll
    for (int q = 0; q < 4; ++q) {
      const int rr = row0 + kg * 4 + q;
      const float di = (rr < n) ? dinv[rr] : 0.f;
#pragma unroll
      for (int ct = 0; ct < 4; ++ct)
        sh.g[wvq][(kg * 4 + q) * NDIM + ct * 16 + lrow] =
            (ushort)f2bf_rne(acc[ct][q] * di);
    }
    // same-wave LDS write->read: compiler-inserted lgkmcnt orders it (R7/R9)
#pragma unroll
    for (int e = 0; e < 2; ++e) {
      const int idx = e * 64 + l;
      const int rw = idx >> 3;
      if (row0 + rw < n)
        ((uint4*)hsb)[(size_t)(row0 + rw) * 8 + (idx & 7)] =
            ((const uint4*)sh.g[wvq])[idx];
    }
  }
}

// ---- hsb = bf16((Xb @ W) * dinv[row]) via MFMA (bf16 input, layer 2) ----
__global__ __launch_bounds__(256) void gemm_mfma_bf16_kernel(
    const ushort* __restrict__ Xin, const float* __restrict__ W,
    const float* __restrict__ dinv, ushort* __restrict__ hsb, int nrows) {
  __shared__ __attribute__((aligned(16))) ushort stage[4][16 * NDIM];
  const int tid = threadIdx.x;
  const int l = tid & 63;
  const int wv = tid >> 6;
  const int lrow = l & 15;
  const int kg = l >> 4;

  short8b Whi[4][2], Wlo[4][2];
#pragma unroll
  for (int ct = 0; ct < 4; ++ct) {
#pragma unroll
    for (int ks = 0; ks < 2; ++ks) {
      const int c = ct * 16 + lrow;
      const int k0 = ks * 32 + kg * 8;
#pragma unroll
      for (int i = 0; i < 8; ++i) {
        float w = W[(k0 + i) * NDIM + c];
        unsigned hb = f2bf_rne(w);
        float hf = __uint_as_float(hb << 16);
        Whi[ct][ks][i] = (short)hb;
        Wlo[ct][ks][i] = (short)f2bf_rne(w - hf);
      }
    }
  }

  const int tiles = (nrows + 15) >> 4;
  for (int tb = blockIdx.x * 4; tb < tiles; tb += gridDim.x * 4) {
    const int t = tb + wv;
    const int row0 = t << 4;
    const int r = row0 + lrow;
    short8b Ahi[2];
    const uint4* Xb = (const uint4*)Xin;
#pragma unroll
    for (int ks = 0; ks < 2; ++ks) {
      uint4 q = make_uint4(0u, 0u, 0u, 0u);
      if (r < nrows) q = Xb[(size_t)r * 8 + ks * 4 + kg];
      union { uint4 u; short8b s; } cv; cv.u = q;
      Ahi[ks] = cv.s;
    }
    f32x4 acc[4];
#pragma unroll
    for (int ct = 0; ct < 4; ++ct) {
      f32x4 a = {0.f, 0.f, 0.f, 0.f};
#pragma unroll
      for (int ks = 0; ks < 2; ++ks) {
        a = __builtin_amdgcn_mfma_f32_16x16x32_bf16(Ahi[ks], Whi[ct][ks], a, 0, 0, 0);
        a = __builtin_amdgcn_mfma_f32_16x16x32_bf16(Ahi[ks], Wlo[ct][ks], a, 0, 0, 0);
      }
      acc[ct] = a;
    }
#pragma unroll
    for (int q = 0; q < 4; ++q) {
      const int rr = row0 + kg * 4 + q;
      const float di = (rr < nrows) ? dinv[rr] : 0.f;
#pragma unroll
      for (int ct = 0; ct < 4; ++ct)
        stage[wv][(kg * 4 + q) * NDIM + ct * 16 + lrow] =
            (ushort)f2bf_rne(acc[ct][q] * di);
    }
    __syncthreads();
#pragma unroll
    for (int e = 0; e < 2; ++e) {
      const int idx = e * 64 + l;
      const int rw = idx >> 3;
      if (row0 + rw < nrows)
        ((uint4*)hsb)[(size_t)(row0 + rw) * 8 + (idx & 7)] =
            ((const uint4*)stage[wv])[idx];
    }
    __syncthreads();
  }
}

__device__ __forceinline__ void add8(v2f* acc, uint4 q) {
  v2f a0, a1, a2, a3;
  a0.x = __uint_as_float(q.x << 16); a0.y = __uint_as_float(q.x & 0xffff0000u);
  a1.x = __uint_as_float(q.y << 16); a1.y = __uint_as_float(q.y & 0xffff0000u);
  a2.x = __uint_as_float(q.z << 16); a2.y = __uint_as_float(q.z & 0xffff0000u);
  a3.x = __uint_as_float(q.w << 16); a3.y = __uint_as_float(q.w & 0xffff0000u);
  acc[0] += a0; acc[1] += a1; acc[2] += a2; acc[3] += a3;  // v_pk_add_f32
}

// ---- fused aggregate + epilogue v2 (R8-proven): 4 nodes per wave ----
template <bool BF16OUT>
__global__ __launch_bounds__(256) void agg_epi_kernel(
    const int* __restrict__ rowbeg, const int* __restrict__ rowend,
    const int* __restrict__ csr_src, const uint4* __restrict__ hsb4,
    const float* __restrict__ dinv, const float4* __restrict__ b4,
    void* __restrict__ outp, int n) {
  const int l = threadIdx.x & 63;
  const int wv = threadIdx.x >> 6;
  const int ql = l & 15;             // lane within quarter
  const int sg = ql >> 3;            // subgroup 0/1 within quarter
  const int g = ql & 7;              // column octet
  const int node = blockIdx.x * 16 + wv * 4 + (l >> 4);
  const bool alive = node < n;
  const int nodec = alive ? node : 0;
  int beg = rowbeg[nodec], end = rowend[nodec];
  if (!alive) { beg = 0; end = 0; }
  const int deg = end - beg;
  int dmax = deg;
  dmax = max(dmax, __shfl_xor(dmax, 16));
  dmax = max(dmax, __shfl_xor(dmax, 32));

  v2f acc[4];
#pragma unroll
  for (int i = 0; i < 4; ++i) acc[i] = (v2f)(0.f);

  for (int base = 0; base < dmax; base += 16) {   // wave-uniform trip count
    const int rem = deg - base;                   // per-quarter remaining
    int eidx = (ql < rem) ? csr_src[beg + base + ql] : 0;
#pragma unroll
    for (int j = 0; j < 16; j += 2) {
      const int e = j + sg;
      int s = __shfl(eidx, (l & 48) + e);         // 0 when e >= rem (safe)
      uint4 q = hsb4[(size_t)s * 8 + g];          // unguarded: MLP, row 0 = L1 hit
      if (e < rem) add8(acc, q);
    }
  }
  if (sg == 0) add8(acc, hsb4[(size_t)nodec * 8 + g]);  // self-loop

  float a[8];
#pragma unroll
  for (int i = 0; i < 4; ++i) { a[2 * i] = acc[i].x; a[2 * i + 1] = acc[i].y; }
#pragma unroll
  for (int i = 0; i < 8; ++i) a[i] += __shfl_xor(a[i], 8);  // single level

  if (sg == 0 && alive) {  // quarter lanes 0..7 own cols 8g..8g+7
    float di = dinv[node];
    float4 bb0 = b4[2 * g], bb1 = b4[2 * g + 1];
    float o[8];
    o[0] = fmaxf(di * a[0] + bb0.x, 0.f);
    o[1] = fmaxf(di * a[1] + bb0.y, 0.f);
    o[2] = fmaxf(di * a[2] + bb0.z, 0.f);
    o[3] = fmaxf(di * a[3] + bb0.w, 0.f);
    o[4] = fmaxf(di * a[4] + bb1.x, 0.f);
    o[5] = fmaxf(di * a[5] + bb1.y, 0.f);
    o[6] = fmaxf(di * a[6] + bb1.z, 0.f);
    o[7] = fmaxf(di * a[7] + bb1.w, 0.f);
    if (BF16OUT) {
      uint4 wvv;
      wvv.x = f2bf_rne(o[0]) | (f2bf_rne(o[1]) << 16);
      wvv.y = f2bf_rne(o[2]) | (f2bf_rne(o[3]) << 16);
      wvv.z = f2bf_rne(o[4]) | (f2bf_rne(o[5]) << 16);
      wvv.w = f2bf_rne(o[6]) | (f2bf_rne(o[7]) << 16);
      ((uint4*)outp)[(size_t)node * 8 + g] = wvv;
    } else {
      float4 o0 = make_float4(o[0], o[1], o[2], o[3]);
      float4 o1 = make_float4(o[4], o[5], o[6], o[7]);
      ((float4*)outp)[(size_t)node * 16 + 2 * g] = o0;
      ((float4*)outp)[(size_t)node * 16 + 2 * g + 1] = o1;
    }
  }
}

extern "C" void kernel_launch(void* const* d_in, const int* in_sizes, int n_in,
                              void* d_out, int out_size, void* d_ws, size_t ws_size,
                              hipStream_t stream) {
  const float* x  = (const float*)d_in[0];
  const int* eidx = (const int*)d_in[1];  // [2, E]
  const float* W1 = (const float*)d_in[2];
  const float* b1 = (const float*)d_in[3];
  const float* W2 = (const float*)d_in[4];
  const float* b2 = (const float*)d_in[5];
  float* out = (float*)d_out;

  const int N = in_sizes[0] / NDIM;  // 100000 (< 2^17 required by packing)
  const int E = in_sizes[1] / 2;     // 1600000
  const int* src = eidx;
  const int* dst = eidx + E;
  const int NV = N * NDIM;
  const int nbuck = (N + BNODES - 1) >> BSHIFT;   // 196 (<=256 required)
  const int nchunk = (E + CHUNK - 1) / CHUNK;     // 391 (<=MAXCHUNK required)

  // workspace layout — every chunk 128B-aligned so hsb rows are line-aligned
  auto al128 = [](size_t v) { return (v + 127) & ~(size_t)127; };
  char* w = (char*)d_ws;
  unsigned* binned = (unsigned*)w;  w += al128(((size_t)nbuck * nchunk) << (CSHIFT + 2));
  int*   cnt     = (int*)w;    w += al128((size_t)nbuck * nchunk * 4);
  int*   csr_src = (int*)w;    w += al128((size_t)nbuck * BCAP * 4);
  int*   rowbeg  = (int*)w;    w += al128((size_t)N * 4);
  int*   rowend  = (int*)w;    w += al128((size_t)N * 4);
  float* dinv    = (float*)w;  w += al128((size_t)N * 4);
  ushort* hsb = (ushort*)w;  w += al128((size_t)NV * 2);
  ushort* h2b = (ushort*)w;  // NV * 2

  // co-resident grid for the cooperative front (host-side, once)
  static int nblk = 0;
  if (nblk == 0) {
    int perCU = 0;
    hipOccupancyMaxActiveBlocksPerMultiprocessor(
        &perCU, reinterpret_cast<const void*>(front_kernel), 256, 0);
    if (perCU < 1) perCU = 1;
    hipDeviceProp_t prop{};
    int ncu = 256;
    if (hipGetDeviceProperties(&prop, 0) == hipSuccess &&
        prop.multiProcessorCount > 0)
      ncu = prop.multiProcessorCount;
    nblk = perCU * ncu;
    if (nblk > 512) nblk = 512;   // gemm1 grid target; bin/csr grid-stride
  }

  const int* p_src = src;  const int* p_dst = dst;
  unsigned* p_binned = binned; int* p_cnt = cnt;
  int* p_rowbeg = rowbeg;  int* p_rowend = rowend;
  int* p_csr = csr_src;    float* p_dinv = dinv;
  const float* p_x = x;    const float* p_W1 = W1;
  ushort* p_hsb = hsb;
  int p_n = N, p_e = E, p_nbuck = nbuck, p_nchunk = nchunk;
  void* args[] = {&p_src, &p_dst, &p_binned, &p_cnt,
                  &p_rowbeg, &p_rowend, &p_csr, &p_dinv,
                  &p_x, &p_W1, &p_hsb,
                  &p_n, &p_e, &p_nbuck, &p_nchunk};
  hipLaunchCooperativeKernel(reinterpret_cast<const void*>(front_kernel),
                             dim3(nblk), dim3(256), args, 0, stream);

  // ---- layer 1 aggregate ----
  agg_epi_kernel<true><<<(N + 15) / 16, 256, 0, stream>>>(
      rowbeg, rowend, csr_src, (const uint4*)hsb, dinv, (const float4*)b1, h2b, N);
  // ---- layer 2 ----
  gemm_mfma_bf16_kernel<<<512, 256, 0, stream>>>(h2b, W2, dinv, hsb, N);
  agg_epi_kernel<false><<<(N + 15) / 16, 256, 0, stream>>>(
      rowbeg, rowend, csr_src, (const uint4*)hsb, dinv, (const float4*)b2, out, N);
}

// Round 11
// 264.048 us; speedup vs baseline: 1.1993x; 1.1993x over previous
//
#include <hip/hip_runtime.h>
#include <hip/hip_bf16.h>

// GCN 2-layer (R11): 6-dispatch split pipeline (R8 skeleton).
//   bin(cursor-free) -> csr(+degree perm) -> gemm1 -> agg1 -> gemm2 -> agg2
// R5/R9/R10 lessons (final): NO coop mega/front kernels, NO fusing compute
// into grid-limited kernels — every co-scheduling attempt lost >> the
// ~14us/boundary it saved. R7 lesson: no fusion across degree-variance
// barriers. R2/R3 lesson: NO LDS float atomics.
// New in R11:
//  - DEGREE-SORTED PERM: csr_build counting-sorts each bucket's nodes by
//    degree; agg processes nodes in perm order so a wave's 4 quarters have
//    near-equal degree -> trip count ceil(max4(deg)/16) ~= ceil(deg/16),
//    cutting ~25% masked gather/add slots (R8 waste model: max4(Poi 16.3)
//    ~24 -> 2 batches for ~16 useful edges).
//  - cursor-free bin (R9-proven) + wave-per-cell COALESCED csr reads
//    (fixes R9's 3x slot-scan amplification) -> memset dispatch gone.
// CSR rows phase-sorted by src>>13 (FETCH 159->88 MB, R4-proven).
// agg: 4 nodes/wave, 16-lane quarters, 8 gathers in flight (R8-proven).
// GEMM: MFMA bf16 hi/lo split (fp32-equivalent accuracy).

#define NDIM 64
#define BSHIFT 9                 // 512 nodes per bucket
#define BNODES (1 << BSHIFT)
#define BCAP 10240               // csr edge capacity per bucket (avg 8163)
#define CHUNK 4096               // edges per binning block
#define CAPC 64                  // slots per (bucket,chunk) cell (avg ~21)
#define CSHIFT 6
#define MAXCHUNK 512             // ccnt LDS bound (nchunk = 391)
#define PHASES 13                // src phase = src >> PSHIFT; 13*8192 >= N
#define PSHIFT 13

typedef float v2f __attribute__((ext_vector_type(2)));
typedef __attribute__((ext_vector_type(8))) short short8b;  // 8 bf16
typedef __attribute__((ext_vector_type(4))) float f32x4;

__device__ __forceinline__ unsigned f2bf_rne(float f) {
  unsigned u = __float_as_uint(f);
  return (u + 0x7fffu + ((u >> 16) & 1u)) >> 16;  // RNE (finite values only)
}

// ---- binning, cursor-free (R9-proven): chunk c partitions its edges by
//      bucket in LDS, writes runs to binned[(b*nchunk+c)*CAPC..] and the
//      count to cnt[b*nchunk+c]. No init, no global atomics. ----
__global__ __launch_bounds__(256) void bin_scatter_kernel(
    const int* __restrict__ src, const int* __restrict__ dst,
    unsigned* __restrict__ binned, int* __restrict__ cnt,
    int nedges, int nchunk, int nbuck) {
  __shared__ int lcnt[256], lbase[256], lcur[256], tscan[256];
  __shared__ int2 stage[CHUNK];
  const int t = threadIdx.x;
  const int c = blockIdx.x;
  const int i0 = c * CHUNK;
  int iend = i0 + CHUNK; if (iend > nedges) iend = nedges;
  lcnt[t] = 0;
  __syncthreads();
  for (int i = i0 + t; i < iend; i += 256)
    atomicAdd(&lcnt[dst[i] >> BSHIFT], 1);
  __syncthreads();
  tscan[t] = lcnt[t];
  __syncthreads();
  for (int off = 1; off < 256; off <<= 1) {
    int tv = (t >= off) ? tscan[t - off] : 0;
    __syncthreads();
    tscan[t] += tv;
    __syncthreads();
  }
  lbase[t] = tscan[t] - lcnt[t];
  lcur[t] = lbase[t];
  __syncthreads();
  for (int i = i0 + t; i < iend; i += 256) {
    int s = src[i], d = dst[i];
    int p = atomicAdd(&lcur[d >> BSHIFT], 1);
    stage[p] = make_int2(s, d);
  }
  __syncthreads();
  const int m = iend - i0;
  for (int i = t; i < m; i += 256) {
    int2 pr = stage[i];
    int b = pr.y >> BSHIFT;
    int off = i - lbase[b];
    if (off < CAPC)   // Poisson(20.9): P(>64) astronomically small
      binned[(((size_t)b * nchunk + c) << CSHIFT) + off] =
          (((unsigned)(pr.y & (BNODES - 1))) << 17) | (unsigned)pr.x;
  }
  if (t < nbuck) cnt[t * nchunk + c] = (lcnt[t] < CAPC) ? lcnt[t] : CAPC;
}

// ---- per-bucket CSR build: wave-per-cell coalesced reads, rows
//      phase-sorted, degree-sorted node perm emitted ----
__global__ __launch_bounds__(256) void csr_build_kernel(
    const unsigned* __restrict__ binned, const int* __restrict__ cnt,
    int* __restrict__ rowbeg, int* __restrict__ rowend,
    int* __restrict__ csr_src, float* __restrict__ dinv,
    int* __restrict__ perm, int n, int nchunk) {
  __shared__ int deg[BNODES], rpl[BNODES], tscan[256], ccnt[MAXCHUNK];
  __shared__ int pcnt[BNODES * PHASES];   // 26.6 KB; total ~34.5 KB
  __shared__ int dhist[64], dcur[64];
  const int b = blockIdx.x, t = threadIdx.x;
  const int wv = t >> 6, l = t & 63;
  const int node0 = b << BSHIFT;
  int ncnt = n - node0; if (ncnt > BNODES) ncnt = BNODES;
  const int e0 = b * BCAP;
  const size_t bbase = ((size_t)b * nchunk) << CSHIFT;

  for (int i = t; i < BNODES * PHASES; i += 256) pcnt[i] = 0;
  for (int i = t; i < nchunk; i += 256) ccnt[i] = cnt[b * nchunk + i];
  if (t < 64) dhist[t] = 0;
  __syncthreads();
  // (node,phase) histogram — wave-per-cell, lanes coalesced over the cell
  for (int c = wv; c < nchunk; c += 4) {
    if (l < ccnt[c]) {
      unsigned u = binned[bbase + ((size_t)c << CSHIFT) + l];
      atomicAdd(&pcnt[(u >> 17) * PHASES + ((u & 0x1FFFFu) >> PSHIFT)], 1);
    }
  }
  __syncthreads();
  for (int i = t; i < BNODES; i += 256) {  // per-node exclusive phase scan
    int s = 0;
#pragma unroll
    for (int p = 0; p < PHASES; ++p) {
      int cv = pcnt[i * PHASES + p];
      pcnt[i * PHASES + p] = s;
      s += cv;
    }
    deg[i] = s;
  }
  __syncthreads();
  int d0 = deg[2 * t], d1 = deg[2 * t + 1];
  int ps = d0 + d1;
  tscan[t] = ps;
  __syncthreads();
  for (int off = 1; off < 256; off <<= 1) {
    int tv = (t >= off) ? tscan[t - off] : 0;
    __syncthreads();
    tscan[t] += tv;
    __syncthreads();
  }
  int eb = tscan[t] - ps;
  rpl[2 * t] = eb;
  rpl[2 * t + 1] = eb + d0;
  __syncthreads();
  for (int i = t; i < ncnt; i += 256) {
    rowbeg[node0 + i] = e0 + rpl[i];
    rowend[node0 + i] = e0 + rpl[i] + deg[i];
    dinv[node0 + i] = rsqrtf((float)deg[i] + 1.0f);
    atomicAdd(&dhist[min(deg[i], 63)], 1);   // degree histogram (key clamped)
  }
  __syncthreads();
  if (t == 0) {   // tiny serial exclusive scan over 64 degree keys
    int run = 0;
    for (int j = 0; j < 64; ++j) { dcur[j] = run; run += dhist[j]; }
  }
  __syncthreads();
  // degree-sorted perm: bijection on [node0, node0+ncnt)
  for (int i = t; i < ncnt; i += 256) {
    int r = atomicAdd(&dcur[min(deg[i], 63)], 1);
    perm[node0 + r] = node0 + i;
  }
  // phase-sorted scatter — wave-per-cell, lanes coalesced
  for (int c = wv; c < nchunk; c += 4) {
    if (l < ccnt[c]) {
      unsigned u = binned[bbase + ((size_t)c << CSHIFT) + l];
      int nd = u >> 17;
      int s = (int)(u & 0x1FFFFu);
      int pos = rpl[nd] + atomicAdd(&pcnt[nd * PHASES + (s >> PSHIFT)], 1);
      csr_src[e0 + pos] = s;
    }
  }
}

// ---- hsb = bf16((X @ W) * dinv[row]) via MFMA, hi/lo bf16 split ----
template <bool BF16IN>
__global__ __launch_bounds__(256) void gemm_mfma_kernel(
    const void* __restrict__ Xin, const float* __restrict__ W,
    const float* __restrict__ dinv, ushort* __restrict__ hsb, int nrows) {
  __shared__ __attribute__((aligned(16))) ushort stage[4][16 * NDIM];
  const int tid = threadIdx.x;
  const int l = tid & 63;
  const int wv = tid >> 6;
  const int lrow = l & 15;   // A row / D col within tile
  const int kg = l >> 4;     // k-group

  short8b Whi[4][2], Wlo[4][2];
#pragma unroll
  for (int ct = 0; ct < 4; ++ct) {
#pragma unroll
    for (int ks = 0; ks < 2; ++ks) {
      const int c = ct * 16 + lrow;
      const int k0 = ks * 32 + kg * 8;
#pragma unroll
      for (int i = 0; i < 8; ++i) {
        float w = W[(k0 + i) * NDIM + c];
        unsigned hb = f2bf_rne(w);
        float hf = __uint_as_float(hb << 16);
        Whi[ct][ks][i] = (short)hb;
        Wlo[ct][ks][i] = (short)f2bf_rne(w - hf);
      }
    }
  }

  const int tiles = (nrows + 15) >> 4;
  for (int tb = blockIdx.x * 4; tb < tiles; tb += gridDim.x * 4) {
    const int t = tb + wv;
    const int row0 = t << 4;
    const int r = row0 + lrow;
    short8b Ahi[2], Alo[2];
    if (BF16IN) {
      const uint4* Xb = (const uint4*)Xin;
#pragma unroll
      for (int ks = 0; ks < 2; ++ks) {
        uint4 q = make_uint4(0u, 0u, 0u, 0u);
        if (r < nrows) q = Xb[(size_t)r * 8 + ks * 4 + kg];
        union { uint4 u; short8b s; } cv; cv.u = q;
        Ahi[ks] = cv.s;
        Alo[ks] = cv.s;  // unused
      }
    } else {
      const float4* Xf = (const float4*)Xin;
#pragma unroll
      for (int ks = 0; ks < 2; ++ks) {
        float4 xa = make_float4(0.f, 0.f, 0.f, 0.f);
        float4 xb = make_float4(0.f, 0.f, 0.f, 0.f);
        if (r < nrows) {
          xa = Xf[(size_t)r * 16 + ks * 8 + kg * 2];
          xb = Xf[(size_t)r * 16 + ks * 8 + kg * 2 + 1];
        }
        float xs[8] = {xa.x, xa.y, xa.z, xa.w, xb.x, xb.y, xb.z, xb.w};
#pragma unroll
        for (int i = 0; i < 8; ++i) {
          unsigned hb = f2bf_rne(xs[i]);
          float hf = __uint_as_float(hb << 16);
          Ahi[ks][i] = (short)hb;
          Alo[ks][i] = (short)f2bf_rne(xs[i] - hf);
        }
      }
    }
    f32x4 acc[4];
#pragma unroll
    for (int ct = 0; ct < 4; ++ct) {
      f32x4 a = {0.f, 0.f, 0.f, 0.f};
#pragma unroll
      for (int ks = 0; ks < 2; ++ks) {
        a = __builtin_amdgcn_mfma_f32_16x16x32_bf16(Ahi[ks], Whi[ct][ks], a, 0, 0, 0);
        a = __builtin_amdgcn_mfma_f32_16x16x32_bf16(Ahi[ks], Wlo[ct][ks], a, 0, 0, 0);
        if (!BF16IN)
          a = __builtin_amdgcn_mfma_f32_16x16x32_bf16(Alo[ks], Whi[ct][ks], a, 0, 0, 0);
      }
      acc[ct] = a;
    }
#pragma unroll
    for (int q = 0; q < 4; ++q) {
      const int rr = row0 + kg * 4 + q;
      const float di = (rr < nrows) ? dinv[rr] : 0.f;
#pragma unroll
      for (int ct = 0; ct < 4; ++ct)
        stage[wv][(kg * 4 + q) * NDIM + ct * 16 + lrow] =
            (ushort)f2bf_rne(acc[ct][q] * di);
    }
    __syncthreads();
#pragma unroll
    for (int e = 0; e < 2; ++e) {
      const int idx = e * 64 + l;
      const int rw = idx >> 3;
      if (row0 + rw < nrows)
        ((uint4*)hsb)[(size_t)(row0 + rw) * 8 + (idx & 7)] =
            ((const uint4*)stage[wv])[idx];
    }
    __syncthreads();
  }
}

__device__ __forceinline__ void add8(v2f* acc, uint4 q) {
  v2f a0, a1, a2, a3;
  a0.x = __uint_as_float(q.x << 16); a0.y = __uint_as_float(q.x & 0xffff0000u);
  a1.x = __uint_as_float(q.y << 16); a1.y = __uint_as_float(q.y & 0xffff0000u);
  a2.x = __uint_as_float(q.z << 16); a2.y = __uint_as_float(q.z & 0xffff0000u);
  a3.x = __uint_as_float(q.w << 16); a3.y = __uint_as_float(q.w & 0xffff0000u);
  acc[0] += a0; acc[1] += a1; acc[2] += a2; acc[3] += a3;  // v_pk_add_f32
}

// ---- fused aggregate + epilogue v2 + degree-sorted scheduling ----
// 4 nodes/wave via perm: the wave's quarters get 4 consecutive perm slots
// (near-equal degree) -> dmax ~= deg, minimal masked slots. Writes go to
// the node's real row (128B contiguous per quarter, coalescing unchanged).
template <bool BF16OUT>
__global__ __launch_bounds__(256) void agg_epi_kernel(
    const int* __restrict__ perm,
    const int* __restrict__ rowbeg, const int* __restrict__ rowend,
    const int* __restrict__ csr_src, const uint4* __restrict__ hsb4,
    const float* __restrict__ dinv, const float4* __restrict__ b4,
    void* __restrict__ outp, int n) {
  const int l = threadIdx.x & 63;
  const int wv = threadIdx.x >> 6;
  const int ql = l & 15;             // lane within quarter
  const int sg = ql >> 3;            // subgroup 0/1 within quarter
  const int g = ql & 7;              // column octet
  const int qid = blockIdx.x * 16 + wv * 4 + (l >> 4);
  const bool alive = qid < n;
  const int node = alive ? perm[qid] : 0;   // perm: bijection on [0,n)
  int beg = rowbeg[node], end = rowend[node];
  if (!alive) { beg = 0; end = 0; }
  const int deg = end - beg;
  int dmax = deg;
  dmax = max(dmax, __shfl_xor(dmax, 16));
  dmax = max(dmax, __shfl_xor(dmax, 32));

  v2f acc[4];
#pragma unroll
  for (int i = 0; i < 4; ++i) acc[i] = (v2f)(0.f);

  for (int base = 0; base < dmax; base += 16) {   // wave-uniform trip count
    const int rem = deg - base;                   // per-quarter remaining
    int eidx = (ql < rem) ? csr_src[beg + base + ql] : 0;
#pragma unroll
    for (int j = 0; j < 16; j += 2) {
      const int e = j + sg;
      int s = __shfl(eidx, (l & 48) + e);         // 0 when e >= rem (safe)
      uint4 q = hsb4[(size_t)s * 8 + g];          // unguarded: MLP, row 0 = L1 hit
      if (e < rem) add8(acc, q);
    }
  }
  if (sg == 0) add8(acc, hsb4[(size_t)node * 8 + g]);  // self-loop

  float a[8];
#pragma unroll
  for (int i = 0; i < 4; ++i) { a[2 * i] = acc[i].x; a[2 * i + 1] = acc[i].y; }
#pragma unroll
  for (int i = 0; i < 8; ++i) a[i] += __shfl_xor(a[i], 8);  // single level

  if (sg == 0 && alive) {  // quarter lanes 0..7 own cols 8g..8g+7
    float di = dinv[node];
    float4 bb0 = b4[2 * g], bb1 = b4[2 * g + 1];
    float o[8];
    o[0] = fmaxf(di * a[0] + bb0.x, 0.f);
    o[1] = fmaxf(di * a[1] + bb0.y, 0.f);
    o[2] = fmaxf(di * a[2] + bb0.z, 0.f);
    o[3] = fmaxf(di * a[3] + bb0.w, 0.f);
    o[4] = fmaxf(di * a[4] + bb1.x, 0.f);
    o[5] = fmaxf(di * a[5] + bb1.y, 0.f);
    o[6] = fmaxf(di * a[6] + bb1.z, 0.f);
    o[7] = fmaxf(di * a[7] + bb1.w, 0.f);
    if (BF16OUT) {
      uint4 wvv;
      wvv.x = f2bf_rne(o[0]) | (f2bf_rne(o[1]) << 16);
      wvv.y = f2bf_rne(o[2]) | (f2bf_rne(o[3]) << 16);
      wvv.z = f2bf_rne(o[4]) | (f2bf_rne(o[5]) << 16);
      wvv.w = f2bf_rne(o[6]) | (f2bf_rne(o[7]) << 16);
      ((uint4*)outp)[(size_t)node * 8 + g] = wvv;
    } else {
      float4 o0 = make_float4(o[0], o[1], o[2], o[3]);
      float4 o1 = make_float4(o[4], o[5], o[6], o[7]);
      ((float4*)outp)[(size_t)node * 16 + 2 * g] = o0;
      ((float4*)outp)[(size_t)node * 16 + 2 * g + 1] = o1;
    }
  }
}

extern "C" void kernel_launch(void* const* d_in, const int* in_sizes, int n_in,
                              void* d_out, int out_size, void* d_ws, size_t ws_size,
                              hipStream_t stream) {
  const float* x  = (const float*)d_in[0];
  const int* eidx = (const int*)d_in[1];  // [2, E]
  const float* W1 = (const float*)d_in[2];
  const float* b1 = (const float*)d_in[3];
  const float* W2 = (const float*)d_in[4];
  const float* b2 = (const float*)d_in[5];
  float* out = (float*)d_out;

  const int N = in_sizes[0] / NDIM;  // 100000 (< 2^17 required by packing)
  const int E = in_sizes[1] / 2;     // 1600000
  const int* src = eidx;
  const int* dst = eidx + E;
  const int NV = N * NDIM;
  const int nbuck = (N + BNODES - 1) >> BSHIFT;   // 196 (<=256 required)
  const int nchunk = (E + CHUNK - 1) / CHUNK;     // 391 (<=MAXCHUNK required)

  // workspace layout — every chunk 128B-aligned so hsb rows are line-aligned
  auto al128 = [](size_t v) { return (v + 127) & ~(size_t)127; };
  char* w = (char*)d_ws;
  unsigned* binned = (unsigned*)w;  w += al128(((size_t)nbuck * nchunk) << (CSHIFT + 2));
  int*   cnt     = (int*)w;    w += al128((size_t)nbuck * nchunk * 4);
  int*   csr_src = (int*)w;    w += al128((size_t)nbuck * BCAP * 4);
  int*   rowbeg  = (int*)w;    w += al128((size_t)N * 4);
  int*   rowend  = (int*)w;    w += al128((size_t)N * 4);
  float* dinv    = (float*)w;  w += al128((size_t)N * 4);
  int*   perm    = (int*)w;    w += al128((size_t)N * 4);
  ushort* hsb = (ushort*)w;  w += al128((size_t)NV * 2);
  ushort* h2b = (ushort*)w;  // NV * 2

  // ---- CSR build (cursor-free, rows phase-sorted, degree perm) ----
  bin_scatter_kernel<<<nchunk, 256, 0, stream>>>(src, dst, binned, cnt,
                                                 E, nchunk, nbuck);
  csr_build_kernel<<<nbuck, 256, 0, stream>>>(binned, cnt, rowbeg, rowend,
                                              csr_src, dinv, perm, N, nchunk);

  // ---- layer 1 ----
  gemm_mfma_kernel<false><<<512, 256, 0, stream>>>(x, W1, dinv, hsb, N);
  agg_epi_kernel<true><<<(N + 15) / 16, 256, 0, stream>>>(
      perm, rowbeg, rowend, csr_src, (const uint4*)hsb, dinv,
      (const float4*)b1, h2b, N);

  // ---- layer 2 ----
  gemm_mfma_kernel<true><<<512, 256, 0, stream>>>(h2b, W2, dinv, hsb, N);
  agg_epi_kernel<false><<<(N + 15) / 16, 256, 0, stream>>>(
      perm, rowbeg, rowend, csr_src, (const uint4*)hsb, dinv,
      (const float4*)b2, out, N);
}

// Round 13
// 236.965 us; speedup vs baseline: 1.3364x; 1.1143x over previous
//
#include <hip/hip_runtime.h>
#include <hip/hip_bf16.h>

// GCN 2-layer (R13 = R12 resubmit; R12 bench was an infra failure, container
// died before compile/run — source re-audited vs R8 baseline, no defect).
//   memset(bcursor) -> bin -> csr(+perm) -> gemm1 -> agg1 -> gemm2 -> agg2
// R11 lesson: cursor-free binning poisons the csr read side (3 attempts:
// R9 slot-scan 3x amplification, R10 serial cells, R11 wave-per-cell
// latency chain at <1 block/CU) -> R8's cursor+memset front with DENSE
// coalesced csr reads is the proven fastest; reverted verbatim.
// Single new variable vs R8: csr_build emits a per-bucket degree-sorted
// node perm (64-bin counting sort, ~2us, int LDS only); agg processes
// nodes in perm order so a wave's 4 quarters have near-equal degree ->
// trip count ceil(max4/16) ~= ceil(deg/16), ~25% fewer masked slots.
// Sums bit-identical (perm changes node->wave assignment, not edge order).
// R5/R9/R10: no coop/mega fusion. R7: no fusion across degree variance.
// R2/R3: no LDS float atomics. CSR rows phase-sorted by src>>13
// (FETCH 159->88 MB, R4-proven). agg: 4 nodes/wave, 16-lane quarters,
// 8 gathers in flight (R8-proven). GEMM: MFMA bf16 hi/lo split.

#define NDIM 64
#define BSHIFT 9                 // 512 nodes per bucket
#define BNODES (1 << BSHIFT)
#define BCAP 10240               // edge capacity per bucket (avg 8163, max~8.6k)
#define CHUNK 4096               // edges per binning block
#define PHASES 13                // src phase = src >> PSHIFT; 13*8192 >= N
#define PSHIFT 13

typedef float v2f __attribute__((ext_vector_type(2)));
typedef __attribute__((ext_vector_type(8))) short short8b;  // 8 bf16
typedef __attribute__((ext_vector_type(4))) float f32x4;

__device__ __forceinline__ unsigned f2bf_rne(float f) {
  unsigned u = __float_as_uint(f);
  return (u + 0x7fffu + ((u >> 16) & 1u)) >> 16;  // RNE (finite values only)
}

// ---- binning (R8-verbatim): group chunk's edges by bucket in LDS, write
//      packed ((dst&511)<<17 | src) runs into per-bucket regions.
//      bcursor holds COUNTS (memset 0); absolute base = b*BCAP + count. ----
__global__ __launch_bounds__(256) void bin_scatter_kernel(
    const int* __restrict__ src, const int* __restrict__ dst,
    int* __restrict__ bcursor, unsigned* __restrict__ binned, int nedges) {
  __shared__ int lcnt[256], lbase[256], lcur[256], gbase[256], tscan[256];
  __shared__ int2 stage[CHUNK];
  int t = threadIdx.x;
  int i0 = blockIdx.x * CHUNK;
  int iend = i0 + CHUNK; if (iend > nedges) iend = nedges;
  lcnt[t] = 0;
  __syncthreads();
  for (int i = i0 + t; i < iend; i += 256)
    atomicAdd(&lcnt[dst[i] >> BSHIFT], 1);
  __syncthreads();
  tscan[t] = lcnt[t];
  __syncthreads();
  for (int off = 1; off < 256; off <<= 1) {
    int tv = (t >= off) ? tscan[t - off] : 0;
    __syncthreads();
    tscan[t] += tv;
    __syncthreads();
  }
  lbase[t] = tscan[t] - lcnt[t];
  lcur[t] = lbase[t];
  if (lcnt[t] > 0) gbase[t] = t * BCAP + atomicAdd(&bcursor[t], lcnt[t]);
  __syncthreads();
  for (int i = i0 + t; i < iend; i += 256) {
    int s = src[i], d = dst[i];
    int p = atomicAdd(&lcur[d >> BSHIFT], 1);
    stage[p] = make_int2(s, d);
  }
  __syncthreads();
  int cnt = iend - i0;
  for (int i = t; i < cnt; i += 256) {
    int2 pr = stage[i];
    int b = pr.y >> BSHIFT;
    unsigned pk = (((unsigned)(pr.y & (BNODES - 1))) << 17) | (unsigned)pr.x;
    int idx = gbase[b] + (i - lbase[b]);
    if (idx < (b + 1) * BCAP) binned[idx] = pk;  // guard (uniform input: never)
  }
}

// ---- per-bucket CSR build (R8-verbatim dense reads) + degree perm ----
__global__ __launch_bounds__(256) void csr_build_kernel(
    const unsigned* __restrict__ binned, const int* __restrict__ bcursor,
    int* __restrict__ rowbeg, int* __restrict__ rowend,
    int* __restrict__ csr_src, float* __restrict__ dinv,
    int* __restrict__ perm, int n) {
  __shared__ int deg[BNODES], rpl[BNODES], tscan[256];
  __shared__ int pcnt[BNODES * PHASES];   // 26.6 KB
  __shared__ int dhist[64], dcur[64];
  int b = blockIdx.x, t = threadIdx.x;
  int node0 = b << BSHIFT;
  int ncnt = n - node0; if (ncnt > BNODES) ncnt = BNODES;
  int e0 = b * BCAP;
  int ecnt = bcursor[b];                  // count-only cursor
  if (ecnt > BCAP) ecnt = BCAP;
  for (int i = t; i < BNODES * PHASES; i += 256) pcnt[i] = 0;
  if (t < 64) dhist[t] = 0;
  __syncthreads();
  for (int i = t; i < ecnt; i += 256) {   // dense coalesced (R8-proven)
    unsigned u = binned[e0 + i];
    atomicAdd(&pcnt[(u >> 17) * PHASES + ((u & 0x1FFFFu) >> PSHIFT)], 1);
  }
  __syncthreads();
  for (int i = t; i < BNODES; i += 256) {  // per-node exclusive phase scan
    int s = 0;
#pragma unroll
    for (int p = 0; p < PHASES; ++p) {
      int c = pcnt[i * PHASES + p];
      pcnt[i * PHASES + p] = s;
      s += c;
    }
    deg[i] = s;
  }
  __syncthreads();
  int d0 = deg[2 * t], d1 = deg[2 * t + 1];
  int ps = d0 + d1;
  tscan[t] = ps;
  __syncthreads();
  for (int off = 1; off < 256; off <<= 1) {
    int tv = (t >= off) ? tscan[t - off] : 0;
    __syncthreads();
    tscan[t] += tv;
    __syncthreads();
  }
  int eb = tscan[t] - ps;
  rpl[2 * t] = eb;
  rpl[2 * t + 1] = eb + d0;
  __syncthreads();
  for (int i = t; i < ncnt; i += 256) {
    rowbeg[node0 + i] = e0 + rpl[i];
    rowend[node0 + i] = e0 + rpl[i] + deg[i];
    dinv[node0 + i] = rsqrtf((float)deg[i] + 1.0f);
    atomicAdd(&dhist[min(deg[i], 63)], 1);   // degree histogram
  }
  __syncthreads();
  if (t == 0) {   // tiny serial exclusive scan over 64 degree keys
    int run = 0;
    for (int j = 0; j < 64; ++j) { dcur[j] = run; run += dhist[j]; }
  }
  __syncthreads();
  for (int i = t; i < ncnt; i += 256) {   // degree-sorted perm (bijection)
    int r = atomicAdd(&dcur[min(deg[i], 63)], 1);
    perm[node0 + r] = node0 + i;
  }
  for (int i = t; i < ecnt; i += 256) {   // phase-sorted scatter (R8-verbatim)
    unsigned u = binned[e0 + i];
    int nd = u >> 17;
    int s = (int)(u & 0x1FFFFu);
    int pos = rpl[nd] + atomicAdd(&pcnt[nd * PHASES + (s >> PSHIFT)], 1);
    csr_src[e0 + pos] = s;  // scattered within bucket region (L2-absorbed)
  }
}

// ---- hsb = bf16((X @ W) * dinv[row]) via MFMA, hi/lo bf16 split ----
template <bool BF16IN>
__global__ __launch_bounds__(256) void gemm_mfma_kernel(
    const void* __restrict__ Xin, const float* __restrict__ W,
    const float* __restrict__ dinv, ushort* __restrict__ hsb, int nrows) {
  __shared__ __attribute__((aligned(16))) ushort stage[4][16 * NDIM];
  const int tid = threadIdx.x;
  const int l = tid & 63;
  const int wv = tid >> 6;
  const int lrow = l & 15;   // A row / D col within tile
  const int kg = l >> 4;     // k-group

  short8b Whi[4][2], Wlo[4][2];
#pragma unroll
  for (int ct = 0; ct < 4; ++ct) {
#pragma unroll
    for (int ks = 0; ks < 2; ++ks) {
      const int c = ct * 16 + lrow;
      const int k0 = ks * 32 + kg * 8;
#pragma unroll
      for (int i = 0; i < 8; ++i) {
        float w = W[(k0 + i) * NDIM + c];
        unsigned hb = f2bf_rne(w);
        float hf = __uint_as_float(hb << 16);
        Whi[ct][ks][i] = (short)hb;
        Wlo[ct][ks][i] = (short)f2bf_rne(w - hf);
      }
    }
  }

  const int tiles = (nrows + 15) >> 4;
  for (int tb = blockIdx.x * 4; tb < tiles; tb += gridDim.x * 4) {
    const int t = tb + wv;
    const int row0 = t << 4;
    const int r = row0 + lrow;
    short8b Ahi[2], Alo[2];
    if (BF16IN) {
      const uint4* Xb = (const uint4*)Xin;
#pragma unroll
      for (int ks = 0; ks < 2; ++ks) {
        uint4 q = make_uint4(0u, 0u, 0u, 0u);
        if (r < nrows) q = Xb[(size_t)r * 8 + ks * 4 + kg];
        union { uint4 u; short8b s; } cv; cv.u = q;
        Ahi[ks] = cv.s;
        Alo[ks] = cv.s;  // unused
      }
    } else {
      const float4* Xf = (const float4*)Xin;
#pragma unroll
      for (int ks = 0; ks < 2; ++ks) {
        float4 xa = make_float4(0.f, 0.f, 0.f, 0.f);
        float4 xb = make_float4(0.f, 0.f, 0.f, 0.f);
        if (r < nrows) {
          xa = Xf[(size_t)r * 16 + ks * 8 + kg * 2];
          xb = Xf[(size_t)r * 16 + ks * 8 + kg * 2 + 1];
        }
        float xs[8] = {xa.x, xa.y, xa.z, xa.w, xb.x, xb.y, xb.z, xb.w};
#pragma unroll
        for (int i = 0; i < 8; ++i) {
          unsigned hb = f2bf_rne(xs[i]);
          float hf = __uint_as_float(hb << 16);
          Ahi[ks][i] = (short)hb;
          Alo[ks][i] = (short)f2bf_rne(xs[i] - hf);
        }
      }
    }
    f32x4 acc[4];
#pragma unroll
    for (int ct = 0; ct < 4; ++ct) {
      f32x4 a = {0.f, 0.f, 0.f, 0.f};
#pragma unroll
      for (int ks = 0; ks < 2; ++ks) {
        a = __builtin_amdgcn_mfma_f32_16x16x32_bf16(Ahi[ks], Whi[ct][ks], a, 0, 0, 0);
        a = __builtin_amdgcn_mfma_f32_16x16x32_bf16(Ahi[ks], Wlo[ct][ks], a, 0, 0, 0);
        if (!BF16IN)
          a = __builtin_amdgcn_mfma_f32_16x16x32_bf16(Alo[ks], Whi[ct][ks], a, 0, 0, 0);
      }
      acc[ct] = a;
    }
#pragma unroll
    for (int q = 0; q < 4; ++q) {
      const int rr = row0 + kg * 4 + q;
      const float di = (rr < nrows) ? dinv[rr] : 0.f;
#pragma unroll
      for (int ct = 0; ct < 4; ++ct)
        stage[wv][(kg * 4 + q) * NDIM + ct * 16 + lrow] =
            (ushort)f2bf_rne(acc[ct][q] * di);
    }
    __syncthreads();
#pragma unroll
    for (int e = 0; e < 2; ++e) {
      const int idx = e * 64 + l;
      const int rw = idx >> 3;
      if (row0 + rw < nrows)
        ((uint4*)hsb)[(size_t)(row0 + rw) * 8 + (idx & 7)] =
            ((const uint4*)stage[wv])[idx];
    }
    __syncthreads();
  }
}

__device__ __forceinline__ void add8(v2f* acc, uint4 q) {
  v2f a0, a1, a2, a3;
  a0.x = __uint_as_float(q.x << 16); a0.y = __uint_as_float(q.x & 0xffff0000u);
  a1.x = __uint_as_float(q.y << 16); a1.y = __uint_as_float(q.y & 0xffff0000u);
  a2.x = __uint_as_float(q.z << 16); a2.y = __uint_as_float(q.z & 0xffff0000u);
  a3.x = __uint_as_float(q.w << 16); a3.y = __uint_as_float(q.w & 0xffff0000u);
  acc[0] += a0; acc[1] += a1; acc[2] += a2; acc[3] += a3;  // v_pk_add_f32
}

// ---- fused aggregate + epilogue v2 (R8) + degree-sorted scheduling ----
// 4 nodes/wave via perm: quarters get 4 consecutive perm slots (near-equal
// degree) -> dmax ~= deg. Writes go to the node's real row (128B full-line
// per quarter; scatter at row granularity is HBM-neutral).
template <bool BF16OUT>
__global__ __launch_bounds__(256) void agg_epi_kernel(
    const int* __restrict__ perm,
    const int* __restrict__ rowbeg, const int* __restrict__ rowend,
    const int* __restrict__ csr_src, const uint4* __restrict__ hsb4,
    const float* __restrict__ dinv, const float4* __restrict__ b4,
    void* __restrict__ outp, int n) {
  const int l = threadIdx.x & 63;
  const int wv = threadIdx.x >> 6;
  const int ql = l & 15;             // lane within quarter
  const int sg = ql >> 3;            // subgroup 0/1 within quarter
  const int g = ql & 7;              // column octet
  const int qid = blockIdx.x * 16 + wv * 4 + (l >> 4);
  const bool alive = qid < n;
  const int node = alive ? perm[qid] : 0;   // perm: bijection on [0,n)
  int beg = rowbeg[node], end = rowend[node];
  if (!alive) { beg = 0; end = 0; }
  const int deg = end - beg;
  int dmax = deg;
  dmax = max(dmax, __shfl_xor(dmax, 16));
  dmax = max(dmax, __shfl_xor(dmax, 32));

  v2f acc[4];
#pragma unroll
  for (int i = 0; i < 4; ++i) acc[i] = (v2f)(0.f);

  for (int base = 0; base < dmax; base += 16) {   // wave-uniform trip count
    const int rem = deg - base;                   // per-quarter remaining
    int eidx = (ql < rem) ? csr_src[beg + base + ql] : 0;
#pragma unroll
    for (int j = 0; j < 16; j += 2) {
      const int e = j + sg;
      int s = __shfl(eidx, (l & 48) + e);         // 0 when e >= rem (safe)
      uint4 q = hsb4[(size_t)s * 8 + g];          // unguarded: MLP, row 0 = L1 hit
      if (e < rem) add8(acc, q);
    }
  }
  if (sg == 0) add8(acc, hsb4[(size_t)node * 8 + g]);  // self-loop

  float a[8];
#pragma unroll
  for (int i = 0; i < 4; ++i) { a[2 * i] = acc[i].x; a[2 * i + 1] = acc[i].y; }
#pragma unroll
  for (int i = 0; i < 8; ++i) a[i] += __shfl_xor(a[i], 8);  // single level

  if (sg == 0 && alive) {  // quarter lanes 0..7 own cols 8g..8g+7
    float di = dinv[node];
    float4 bb0 = b4[2 * g], bb1 = b4[2 * g + 1];
    float o[8];
    o[0] = fmaxf(di * a[0] + bb0.x, 0.f);
    o[1] = fmaxf(di * a[1] + bb0.y, 0.f);
    o[2] = fmaxf(di * a[2] + bb0.z, 0.f);
    o[3] = fmaxf(di * a[3] + bb0.w, 0.f);
    o[4] = fmaxf(di * a[4] + bb1.x, 0.f);
    o[5] = fmaxf(di * a[5] + bb1.y, 0.f);
    o[6] = fmaxf(di * a[6] + bb1.z, 0.f);
    o[7] = fmaxf(di * a[7] + bb1.w, 0.f);
    if (BF16OUT) {
      uint4 wvv;
      wvv.x = f2bf_rne(o[0]) | (f2bf_rne(o[1]) << 16);
      wvv.y = f2bf_rne(o[2]) | (f2bf_rne(o[3]) << 16);
      wvv.z = f2bf_rne(o[4]) | (f2bf_rne(o[5]) << 16);
      wvv.w = f2bf_rne(o[6]) | (f2bf_rne(o[7]) << 16);
      ((uint4*)outp)[(size_t)node * 8 + g] = wvv;
    } else {
      float4 o0 = make_float4(o[0], o[1], o[2], o[3]);
      float4 o1 = make_float4(o[4], o[5], o[6], o[7]);
      ((float4*)outp)[(size_t)node * 16 + 2 * g] = o0;
      ((float4*)outp)[(size_t)node * 16 + 2 * g + 1] = o1;
    }
  }
}

extern "C" void kernel_launch(void* const* d_in, const int* in_sizes, int n_in,
                              void* d_out, int out_size, void* d_ws, size_t ws_size,
                              hipStream_t stream) {
  const float* x  = (const float*)d_in[0];
  const int* eidx = (const int*)d_in[1];  // [2, E]
  const float* W1 = (const float*)d_in[2];
  const float* b1 = (const float*)d_in[3];
  const float* W2 = (const float*)d_in[4];
  const float* b2 = (const float*)d_in[5];
  float* out = (float*)d_out;

  const int N = in_sizes[0] / NDIM;  // 100000 (< 2^17 required by packing)
  const int E = in_sizes[1] / 2;     // 1600000
  const int* src = eidx;
  const int* dst = eidx + E;
  const int NV = N * NDIM;
  const int nbuck = (N + BNODES - 1) >> BSHIFT;   // 196 (<=256 required)
  const int nchunk = (E + CHUNK - 1) / CHUNK;

  // workspace layout — every chunk 128B-aligned so hsb rows are line-aligned
  auto al128 = [](size_t v) { return (v + 127) & ~(size_t)127; };
  char* w = (char*)d_ws;
  unsigned* binned = (unsigned*)w;  w += al128((size_t)nbuck * BCAP * 4);
  int*   csr_src = (int*)w;    w += al128((size_t)nbuck * BCAP * 4);
  int*   rowbeg  = (int*)w;    w += al128((size_t)N * 4);
  int*   rowend  = (int*)w;    w += al128((size_t)N * 4);
  float* dinv    = (float*)w;  w += al128((size_t)N * 4);
  int*   perm    = (int*)w;    w += al128((size_t)N * 4);
  int*   bcursor = (int*)w;    w += 2048;
  ushort* hsb = (ushort*)w;  w += al128((size_t)NV * 2);
  ushort* h2b = (ushort*)w;  // NV * 2

  // ---- CSR build (R8 front; rows phase-sorted; degree perm) ----
  hipMemsetAsync(bcursor, 0, 1024, stream);      // count-only cursors
  bin_scatter_kernel<<<nchunk, 256, 0, stream>>>(src, dst, bcursor, binned, E);
  csr_build_kernel<<<nbuck, 256, 0, stream>>>(binned, bcursor, rowbeg, rowend,
                                              csr_src, dinv, perm, N);

  // ---- layer 1 ----
  gemm_mfma_kernel<false><<<512, 256, 0, stream>>>(x, W1, dinv, hsb, N);
  agg_epi_kernel<true><<<(N + 15) / 16, 256, 0, stream>>>(
      perm, rowbeg, rowend, csr_src, (const uint4*)hsb, dinv,
      (const float4*)b1, h2b, N);

  // ---- layer 2 ----
  gemm_mfma_kernel<true><<<512, 256, 0, stream>>>(h2b, W2, dinv, hsb, N);
  agg_epi_kernel<false><<<(N + 15) / 16, 256, 0, stream>>>(
      perm, rowbeg, rowend, csr_src, (const uint4*)hsb, dinv,
      (const float4*)b2, out, N);
}